// Round 1
// baseline (399.324 us; speedup 1.0000x reference)
//
#include <hip/hip_runtime.h>
#include <math.h>

#define BB 16
#define CC 1024
#define SS 4096
#define CCHUNKS 8
#define CPER (CC / CCHUNKS)   // 128
#define SCHUNKS 4
#define SPER (SS / SCHUNKS)   // 1024

// Kernel 1: partial channel-contraction (logit partials).
// grid = (SCHUNKS, CCHUNKS, B), block = 256. Each thread owns 4 consecutive
// spatial positions (float4 loads = 16B/lane), loops CPER channels.
__global__ __launch_bounds__(256) void k_partial_logits(
    const float* __restrict__ x, const float* __restrict__ w,
    float* __restrict__ partial)
{
    const int schunk = blockIdx.x;   // 0..3
    const int cchunk = blockIdx.y;   // 0..7
    const int b      = blockIdx.z;   // 0..15
    const int tid    = threadIdx.x;  // 0..255
    const int s      = schunk * SPER + tid * 4;

    const float* xb = x + (size_t)b * CC * SS;
    const int c0 = cchunk * CPER;

    float4 acc = make_float4(0.f, 0.f, 0.f, 0.f);
    for (int i = 0; i < CPER; ++i) {
        const int c = c0 + i;
        const float wc = w[c];  // uniform address -> scalar load, s-cache
        const float4 xv = *(const float4*)(xb + (size_t)c * SS + s);
        acc.x += xv.x * wc;
        acc.y += xv.y * wc;
        acc.z += xv.z * wc;
        acc.w += xv.w * wc;
    }
    *(float4*)(partial + ((size_t)(b * CCHUNKS + cchunk) * SS + s)) = acc;
}

// Kernel 2: reduce partials -> logits -> softmax over S per batch.
// grid = B, block = 1024 (each thread owns 4 spatial positions).
__global__ __launch_bounds__(1024) void k_softmax(
    const float* __restrict__ partial, const float* __restrict__ bias,
    float* __restrict__ attn)
{
    const int b   = blockIdx.x;
    const int tid = threadIdx.x;      // 0..1023
    const int s   = tid * 4;
    const int wave = tid >> 6;
    const int lane = tid & 63;

    float4 l = make_float4(0.f, 0.f, 0.f, 0.f);
    for (int k = 0; k < CCHUNKS; ++k) {
        const float4 p =
            *(const float4*)(partial + ((size_t)(b * CCHUNKS + k) * SS + s));
        l.x += p.x; l.y += p.y; l.z += p.z; l.w += p.w;
    }
    const float scale = 0.03125f;  // 1/sqrt(1024)
    const float bv = bias[0];
    l.x = (l.x + bv) * scale;
    l.y = (l.y + bv) * scale;
    l.z = (l.z + bv) * scale;
    l.w = (l.w + bv) * scale;

    // block max
    float m = fmaxf(fmaxf(l.x, l.y), fmaxf(l.z, l.w));
    for (int off = 32; off; off >>= 1) m = fmaxf(m, __shfl_down(m, off));
    __shared__ float redm[16];
    __shared__ float reds[16];
    if (lane == 0) redm[wave] = m;
    __syncthreads();
    if (wave == 0) {
        float v = (lane < 16) ? redm[lane] : -INFINITY;
        for (int off = 8; off; off >>= 1) v = fmaxf(v, __shfl_down(v, off));
        if (lane == 0) redm[0] = v;
    }
    __syncthreads();
    const float M = redm[0];

    float4 e;
    e.x = __expf(l.x - M);
    e.y = __expf(l.y - M);
    e.z = __expf(l.z - M);
    e.w = __expf(l.w - M);

    float ssum = (e.x + e.y) + (e.z + e.w);
    for (int off = 32; off; off >>= 1) ssum += __shfl_down(ssum, off);
    if (lane == 0) reds[wave] = ssum;
    __syncthreads();
    if (wave == 0) {
        float v = (lane < 16) ? reds[lane] : 0.f;
        for (int off = 8; off; off >>= 1) v += __shfl_down(v, off);
        if (lane == 0) reds[0] = v;
    }
    __syncthreads();
    const float inv = 1.0f / reds[0];

    float4 a = make_float4(e.x * inv, e.y * inv, e.z * inv, e.w * inv);
    *(float4*)(attn + (size_t)b * SS + s) = a;
}

// Kernel 3: focus[b,c] = sum_s x[b,c,s] * attn[b,s].
// grid = (C/4, B), block = 256 (4 waves; one channel per wave).
// attn[b] staged in LDS (16 KB), reused by all 4 waves.
__global__ __launch_bounds__(256) void k_focus(
    const float* __restrict__ x, const float* __restrict__ attn,
    float* __restrict__ out)
{
    __shared__ float a_lds[SS];  // 16 KB
    const int b    = blockIdx.y;
    const int c    = blockIdx.x * 4 + (threadIdx.x >> 6);
    const int lane = threadIdx.x & 63;

    // stage attn row (coalesced float4)
    for (int i = 0; i < 4; ++i) {
        const int idx = i * 1024 + threadIdx.x * 4;
        *(float4*)(a_lds + idx) = *(const float4*)(attn + (size_t)b * SS + idx);
    }
    __syncthreads();

    const float* xr = x + ((size_t)(b * CC + c) * SS);
    float4 acc = make_float4(0.f, 0.f, 0.f, 0.f);
    for (int j = 0; j < 16; ++j) {
        const int s = j * 256 + lane * 4;
        const float4 xv = *(const float4*)(xr + s);
        const float4 av = *(const float4*)(a_lds + s);
        acc.x += xv.x * av.x;
        acc.y += xv.y * av.y;
        acc.z += xv.z * av.z;
        acc.w += xv.w * av.w;
    }
    float v = (acc.x + acc.y) + (acc.z + acc.w);
    for (int off = 32; off; off >>= 1) v += __shfl_down(v, off);
    if (lane == 0) out[b * CC + c] = v;
}

extern "C" void kernel_launch(void* const* d_in, const int* in_sizes, int n_in,
                              void* d_out, int out_size, void* d_ws, size_t ws_size,
                              hipStream_t stream) {
    const float* x    = (const float*)d_in[0];  // [16,1024,64,64]
    const float* w    = (const float*)d_in[1];  // [1024]
    const float* bias = (const float*)d_in[2];  // [1]
    float* out = (float*)d_out;                 // [16,1024,1,1]

    float* partial = (float*)d_ws;                       // 16*8*4096 f32 = 2 MB
    float* attn    = partial + (size_t)BB * CCHUNKS * SS; // +16*4096 f32 = 256 KB

    k_partial_logits<<<dim3(SCHUNKS, CCHUNKS, BB), 256, 0, stream>>>(x, w, partial);
    k_softmax<<<BB, 1024, 0, stream>>>(partial, bias, attn);
    k_focus<<<dim3(CC / 4, BB), 256, 0, stream>>>(x, attn, out);
}